// Round 17
// baseline (189.534 us; speedup 1.0000x reference)
//
#include <hip/hip_runtime.h>
#include <hip/hip_fp16.h>

// DAA autoencoder — R17 DIAGNOSTIC: R16's 2-kernel pipeline replayed 8x
// (idempotent: every replica writes identical values, outputs unchanged).
// Purpose: measure the marginal warm cost M = (dur - 26.9)/7 of one
// (L0,L1) pair, separating fixed graph/launch overhead from true kernel
// time. 16 rounds of structure changes all land at 25-27us while honest
// arithmetic says the kernels cost ~6us — this round decides which.
//   layer0: h[b][o]   = min_i ( sel0[o][i] ? x[b][i] : 2.0f )
//   layer1: out[b][o] = max_i ( sel1[o][i] ? h[b][i] : -1.0f )
//
// Accuracy unchanged from R15/R16: f32->f16 RN <= 2.44e-4 < 4.10e-4
// threshold (measured 1.22e-4); min/max are selections, no accumulation.

#define H_PINF 0x7C00u
#define H_NINF 0xFC00u

__device__ __forceinline__ unsigned pk_add(unsigned a, unsigned b) {
    unsigned r; asm("v_pk_add_f16 %0, %1, %2" : "=v"(r) : "v"(a), "v"(b)); return r;
}
__device__ __forceinline__ unsigned pk_min(unsigned a, unsigned b) {
    unsigned r; asm("v_pk_min_f16 %0, %1, %2" : "=v"(r) : "v"(a), "v"(b)); return r;
}
__device__ __forceinline__ unsigned pk_max(unsigned a, unsigned b) {
    unsigned r; asm("v_pk_max_f16 %0, %1, %2" : "=v"(r) : "v"(a), "v"(b)); return r;
}
__device__ __forceinline__ unsigned hpk(float a, float b) {
    return (unsigned)__half_as_ushort(__float2half(a))
         | ((unsigned)__half_as_ushort(__float2half(b)) << 16);
}
__device__ __forceinline__ float h2f(unsigned short u) {
    __half h = *reinterpret_cast<__half*>(&u);
    return __half2float(h);
}
__device__ __forceinline__ unsigned selpk(int a, int b, unsigned inf) {
    return (a ? 0u : inf) | ((b ? 0u : inf) << 16);
}

// ===== L0: x[256][1024] f32 + sel0 -> hS slabs ===========================
// block = (j = o-oct 0..63) x (bch 0..3); 1024 threads, 16 waves.
// wave s: output row r = s>>1 (of 8), i-half = s&1; 8 slices of 128 i.
__global__ __launch_bounds__(1024) void daa_l0(
    const float* __restrict__ x, const int* __restrict__ sel0,
    uint4* __restrict__ hS)           // [4][64][64] uint4 (f16 h slab)
{
    __shared__ unsigned aW[8 * 512];           // 8 rows x 1024 halves
    __shared__ uint4 xL[16 * 65];              // slice: 16 ioct x 64 b, pad
    __shared__ unsigned short red[16 * 64];    // per-wave partials
    __shared__ unsigned short mrg[8 * 64];     // merged rows

    const int tid  = threadIdx.x;
    const int lane = tid & 63;
    const int s    = __builtin_amdgcn_readfirstlane(tid >> 6);
    const int bch  = blockIdx.x & 3;
    const int j    = blockIdx.x >> 2;          // o-oct: rows 8j..8j+7
    const int b0   = bch * 64;

    {   // stage sel0 rows 8j..8j+7 as packed f16 addends
        const int4* sp = (const int4*)sel0;    // [512 rows][256 int4]
        const int row = tid >> 7, ch = tid & 127;
        const int4 v0 = sp[(size_t)(8 * j + row) * 256 + ch * 2 + 0];
        const int4 v1 = sp[(size_t)(8 * j + row) * 256 + ch * 2 + 1];
        unsigned* dst = &aW[row * 512 + ch * 4];
        dst[0] = selpk(v0.x, v0.y, H_PINF);
        dst[1] = selpk(v0.z, v0.w, H_PINF);
        dst[2] = selpk(v1.x, v1.y, H_PINF);
        dst[3] = selpk(v1.z, v1.w, H_PINF);
    }

    unsigned acc = hpk(2.0f, 2.0f);
    const int r    = s >> 1;
    const int half = s & 1;

#pragma unroll 1
    for (int t = 0; t < 8; ++t) {              // 8 slices of 128 i
        __syncthreads();
        {   // stage x[b0..b0+63][t*128 .. +127] -> xL[ioct][b] f16
            const int br = tid >> 4;
            const int cg = tid & 15;
            const float* xr = x + (size_t)(b0 + br) * 1024 + t * 128 + cg * 8;
            const float4 f0 = ((const float4*)xr)[0];
            const float4 f1 = ((const float4*)xr)[1];
            uint4 w;
            w.x = hpk(f0.x, f0.y);  w.y = hpk(f0.z, f0.w);
            w.z = hpk(f1.x, f1.y);  w.w = hpk(f1.z, f1.w);
            xL[cg * 65 + br] = w;
        }
        __syncthreads();
        const unsigned* ap = &aW[r * 512 + t * 64 + half * 32];
#pragma unroll
        for (int c = 0; c < 8; ++c) {
            const uint4 xv = xL[(half * 8 + c) * 65 + lane];
            acc = pk_min(acc, pk_add(xv.x, ap[c * 4 + 0]));
            acc = pk_min(acc, pk_add(xv.y, ap[c * 4 + 1]));
            acc = pk_min(acc, pk_add(xv.z, ap[c * 4 + 2]));
            acc = pk_min(acc, pk_add(xv.w, ap[c * 4 + 3]));
        }
    }

    {   // fold hi/lo, publish per-wave partial
        const unsigned f = pk_min(acc, acc >> 16);
        red[s * 64 + lane] = (unsigned short)(f & 0xffffu);
    }
    __syncthreads();

    if (tid < 64) {                            // merge halves + pack oct
#pragma unroll
        for (int rr = 0; rr < 8; ++rr) {
            const unsigned m = pk_min((unsigned)red[(2 * rr + 0) * 64 + tid],
                                      (unsigned)red[(2 * rr + 1) * 64 + tid]);
            mrg[rr * 64 + tid] = (unsigned short)(m & 0xffffu);
        }
        uint4 w;
        w.x = (unsigned)mrg[0 * 64 + tid] | ((unsigned)mrg[1 * 64 + tid] << 16);
        w.y = (unsigned)mrg[2 * 64 + tid] | ((unsigned)mrg[3 * 64 + tid] << 16);
        w.z = (unsigned)mrg[4 * 64 + tid] | ((unsigned)mrg[5 * 64 + tid] << 16);
        w.w = (unsigned)mrg[6 * 64 + tid] | ((unsigned)mrg[7 * 64 + tid] << 16);
        hS[(size_t)bch * 4096 + (size_t)j * 64 + tid] = w;   // coalesced 1 KB
    }
}

// ===== L1: hS slabs + sel1 -> out[256][1024] f32 =========================
// block = (j2 = o-16-tile 0..63) x (bch 0..3); 16 waves = 16 output rows.
__global__ __launch_bounds__(1024) void daa_l1(
    const uint4* __restrict__ hS,     // [4][64][64] uint4
    const int* __restrict__ sel1,
    float* __restrict__ out)
{
    __shared__ unsigned aW[16 * 256];          // 16 rows x 512 halves
    __shared__ float redf[16 * 65];            // padded transpose buffer

    const int tid  = threadIdx.x;
    const int lane = tid & 63;
    const int s    = __builtin_amdgcn_readfirstlane(tid >> 6);
    const int bch  = blockIdx.x & 3;
    const int j2   = blockIdx.x >> 2;          // rows 16*j2 .. +15
    const int b0   = bch * 64;

    {   // stage sel1 rows 16j2..16j2+15 as packed addends
        const int4* sp = (const int4*)sel1;    // [1024 rows][128 int4]
        const int row = tid >> 6, ch = tid & 63;
        const int4 v0 = sp[(size_t)(16 * j2 + row) * 128 + ch * 2 + 0];
        const int4 v1 = sp[(size_t)(16 * j2 + row) * 128 + ch * 2 + 1];
        unsigned* dst = &aW[row * 256 + ch * 4];
        dst[0] = selpk(v0.x, v0.y, H_NINF);
        dst[1] = selpk(v0.z, v0.w, H_NINF);
        dst[2] = selpk(v1.x, v1.y, H_NINF);
        dst[3] = selpk(v1.z, v1.w, H_NINF);
    }
    __syncthreads();

    unsigned acc = hpk(-1.0f, -1.0f);
    const uint4* xp = hS + (size_t)bch * 4096 + lane;
    const unsigned* ap = &aW[s * 256];

#pragma unroll 8
    for (int c = 0; c < 64; ++c) {             // 64 octs of hid
        const uint4 xv = xp[c * 64];           // coalesced 1 KB wave-load
        acc = pk_max(acc, pk_add(xv.x, ap[c * 4 + 0]));
        acc = pk_max(acc, pk_add(xv.y, ap[c * 4 + 1]));
        acc = pk_max(acc, pk_add(xv.z, ap[c * 4 + 2]));
        acc = pk_max(acc, pk_add(xv.w, ap[c * 4 + 3]));
    }

    {   // fold hi/lo -> f32, publish row
        const unsigned f = pk_max(acc, acc >> 16);
        redf[s * 65 + lane] = h2f((unsigned short)(f & 0xffffu));
    }
    __syncthreads();

    {   // transposed store: thread (b = tid&63, oo = tid>>6) -> 64-B segs
        const int b = tid & 63, oo = tid >> 6;
        out[(size_t)(b0 + b) * 1024 + 16 * j2 + oo] = redf[oo * 65 + b];
    }
}

extern "C" void kernel_launch(void* const* d_in, const int* in_sizes, int n_in,
                              void* d_out, int out_size, void* d_ws, size_t ws_size,
                              hipStream_t stream) {
    const float* x    = (const float*)d_in[0];  // [256,1024] f32
    const int*   sel0 = (const int*)d_in[1];    // [512,1024] i32
    const int*   sel1 = (const int*)d_in[2];    // [1024,512] i32
    float* out = (float*)d_out;                 // [256,1024] f32

    uint4* hS = (uint4*)d_ws;                   // 256 KB f16 h slabs

    // DIAGNOSTIC: 8 idempotent replicas of the (L0,L1) pair. Outputs are
    // bit-identical to a single pair; marginal cost per pair =
    // (dur_us - 26.9)/7 decomposes fixed overhead vs true kernel time.
    for (int rep = 0; rep < 8; ++rep) {
        daa_l0<<<256, 1024, 0, stream>>>(x, sel0, hS);
        daa_l1<<<256, 1024, 0, stream>>>(hS, sel1, out);
    }
}

// Round 18
// 21.623 us; speedup vs baseline: 8.7654x; 8.7654x over previous
//
#include <hip/hip_runtime.h>
#include <hip/hip_fp16.h>

// DAA autoencoder — R18: register-blocked 2-kernel pipeline.
//   layer0: h[b][o]   = min_i ( sel0[o][i] ? x[b][i] : 2.0f )
//   layer1: out[b][o] = max_i ( sel1[o][i] ? h[b][i] : -1.0f )
// B=256, IN=1024, HID=512.
//
// R17 measurement: warm (L0,L1) pair = 23.2 us, fixed overhead ~3.7 us ->
// the kernels ARE the cost. Cause: pipe re-crossing. R16-L0 re-read each
// xL byte 8x (one row per wave, ~5us/CU of spread ds_read); R16-L1 re-read
// the 64KB hS slab 16x from global (~8.5us/CU of 1KB wave-loads).
// R18: wave owns an i-chunk and updates ALL rows in registers:
//  L0: acc[8], xv read once per oct, dbuf'd slices (1 barrier/slice).
//  L1: acc[16], slab read once per block into regs (4 loads/wave).
// Epilogue stores coalesced 64-B segments.
//
// Accuracy: identical per-edge values to R15/R16 (f32->f16 RN, +inf/-inf
// addends, exact offsets); min/max order-independent => absmax 1.22e-4.

#define H_PINF 0x7C00u
#define H_NINF 0xFC00u

__device__ __forceinline__ unsigned pk_add(unsigned a, unsigned b) {
    unsigned r; asm("v_pk_add_f16 %0, %1, %2" : "=v"(r) : "v"(a), "v"(b)); return r;
}
__device__ __forceinline__ unsigned pk_min(unsigned a, unsigned b) {
    unsigned r; asm("v_pk_min_f16 %0, %1, %2" : "=v"(r) : "v"(a), "v"(b)); return r;
}
__device__ __forceinline__ unsigned pk_max(unsigned a, unsigned b) {
    unsigned r; asm("v_pk_max_f16 %0, %1, %2" : "=v"(r) : "v"(a), "v"(b)); return r;
}
__device__ __forceinline__ unsigned hpk(float a, float b) {
    return (unsigned)__half_as_ushort(__float2half(a))
         | ((unsigned)__half_as_ushort(__float2half(b)) << 16);
}
__device__ __forceinline__ float h2f(unsigned short u) {
    __half h = *reinterpret_cast<__half*>(&u);
    return __half2float(h);
}
__device__ __forceinline__ unsigned selpk(int a, int b, unsigned inf) {
    return (a ? 0u : inf) | ((b ? 0u : inf) << 16);
}

// ===== L0: x[256][1024] f32 + sel0 -> hS[4][64][64] uint4 f16 slabs ======
// block = (j = o-oct) x (bch); 16 waves. Wave s owns i-oct s of each of 8
// 128-i slices (i = t*128 + s*8 .. +7) and updates all 8 rows (acc[8]).
__global__ __launch_bounds__(1024) void daa_l0(
    const float* __restrict__ x, const int* __restrict__ sel0,
    uint4* __restrict__ hS)
{
    __shared__ unsigned aW[8 * 512];            // 8 rows x 1024 halves, 16 KB
    __shared__ uint4 xL[2][16 * 65];            // dbuf slice, 2 x 16.25 KB
    __shared__ unsigned short red[16 * 8 * 64]; // per-wave partials, 16 KB
    __shared__ unsigned short mrg[8 * 64];      // merged rows

    const int tid  = threadIdx.x;
    const int lane = tid & 63;
    const int s    = __builtin_amdgcn_readfirstlane(tid >> 6);
    const int bch  = blockIdx.x & 3;
    const int j    = blockIdx.x >> 2;           // o rows 8j..8j+7
    const int b0   = bch * 64;

    {   // stage sel0 rows 8j..8j+7 as packed f16 addends
        const int4* sp = (const int4*)sel0;     // [512 rows][256 int4]
        const int row = tid >> 7, ch = tid & 127;
        const int4 v0 = sp[(size_t)(8 * j + row) * 256 + ch * 2 + 0];
        const int4 v1 = sp[(size_t)(8 * j + row) * 256 + ch * 2 + 1];
        unsigned* dst = &aW[row * 512 + ch * 4];
        dst[0] = selpk(v0.x, v0.y, H_PINF);
        dst[1] = selpk(v0.z, v0.w, H_PINF);
        dst[2] = selpk(v1.x, v1.y, H_PINF);
        dst[3] = selpk(v1.z, v1.w, H_PINF);
    }

    // slice staging: thread (br = batch row, cg = oct) converts 8 f32 -> f16
    const int br = tid >> 4, cg = tid & 15;
#define STAGE(T, BUF)                                                      \
    do {                                                                   \
        const float* xr = x + (size_t)(b0 + br) * 1024 + (T) * 128 + cg * 8; \
        const float4 f0 = ((const float4*)xr)[0];                          \
        const float4 f1 = ((const float4*)xr)[1];                          \
        uint4 w;                                                           \
        w.x = hpk(f0.x, f0.y);  w.y = hpk(f0.z, f0.w);                     \
        w.z = hpk(f1.x, f1.y);  w.w = hpk(f1.z, f1.w);                     \
        xL[BUF][cg * 65 + br] = w;                                         \
    } while (0)

    STAGE(0, 0);
    __syncthreads();                    // aW + slice 0 ready

    unsigned acc[8];
#pragma unroll
    for (int r = 0; r < 8; ++r) acc[r] = hpk(2.0f, 2.0f);

#pragma unroll
    for (int t = 0; t < 8; ++t) {
        if (t + 1 < 8) STAGE(t + 1, (t + 1) & 1);   // overlap with compute
        const uint4 xv = xL[t & 1][s * 65 + lane];  // read ONCE, 8 rows use
#pragma unroll
        for (int r = 0; r < 8; ++r) {
            const unsigned* a = &aW[r * 512 + t * 64 + s * 4];  // uniform
            acc[r] = pk_min(acc[r], pk_add(xv.x, a[0]));
            acc[r] = pk_min(acc[r], pk_add(xv.y, a[1]));
            acc[r] = pk_min(acc[r], pk_add(xv.z, a[2]));
            acc[r] = pk_min(acc[r], pk_add(xv.w, a[3]));
        }
        __syncthreads();                // next slice staged + reads done
    }
#undef STAGE

    {   // publish per-wave partials (fold hi/lo halves; lo is valid)
#pragma unroll
        for (int r = 0; r < 8; ++r) {
            const unsigned f = pk_min(acc[r], acc[r] >> 16);
            red[(s * 8 + r) * 64 + lane] = (unsigned short)(f & 0xffffu);
        }
    }
    __syncthreads();

    if (tid < 512) {                    // merge 16 i-chunk partials
        const int u = tid >> 6, ln = tid & 63;
        unsigned m = red[u * 64 + ln];
#pragma unroll
        for (int ss = 1; ss < 16; ++ss)
            m = pk_min(m, (unsigned)red[(ss * 8 + u) * 64 + ln]);
        mrg[u * 64 + ln] = (unsigned short)(m & 0xffffu);
    }
    __syncthreads();

    if (tid < 64) {                     // pack oct -> coalesced uint4 store
        uint4 w;
        w.x = (unsigned)mrg[0 * 64 + tid] | ((unsigned)mrg[1 * 64 + tid] << 16);
        w.y = (unsigned)mrg[2 * 64 + tid] | ((unsigned)mrg[3 * 64 + tid] << 16);
        w.z = (unsigned)mrg[4 * 64 + tid] | ((unsigned)mrg[5 * 64 + tid] << 16);
        w.w = (unsigned)mrg[6 * 64 + tid] | ((unsigned)mrg[7 * 64 + tid] << 16);
        hS[(size_t)bch * 4096 + (size_t)j * 64 + tid] = w;
    }
}

// ===== L1: hS slabs + sel1 -> out[256][1024] f32 =========================
// block = (j2: rows 16j2..+15) x (bch); wave s owns h-octs 4s..4s+3 in
// REGISTERS (slab read once per block) and updates all 16 rows (acc[16]).
__global__ __launch_bounds__(1024) void daa_l1(
    const uint4* __restrict__ hS, const int* __restrict__ sel1,
    float* __restrict__ out)
{
    __shared__ unsigned aW[16 * 256];            // 16 rows x 512 halves, 16 KB
    __shared__ unsigned short red[16 * 16 * 64]; // partials, 32 KB
    __shared__ float redf[16 * 65];              // padded transpose buffer

    const int tid  = threadIdx.x;
    const int lane = tid & 63;
    const int s    = __builtin_amdgcn_readfirstlane(tid >> 6);
    const int bch  = blockIdx.x & 3;
    const int j2   = blockIdx.x >> 2;
    const int b0   = bch * 64;

    {   // stage sel1 rows 16j2..16j2+15 as packed addends
        const int4* sp = (const int4*)sel1;      // [1024 rows][128 int4]
        const int row = tid >> 6, ch = tid & 63;
        const int4 v0 = sp[(size_t)(16 * j2 + row) * 128 + ch * 2 + 0];
        const int4 v1 = sp[(size_t)(16 * j2 + row) * 128 + ch * 2 + 1];
        unsigned* dst = &aW[row * 256 + ch * 4];
        dst[0] = selpk(v0.x, v0.y, H_NINF);
        dst[1] = selpk(v0.z, v0.w, H_NINF);
        dst[2] = selpk(v1.x, v1.y, H_NINF);
        dst[3] = selpk(v1.z, v1.w, H_NINF);
    }

    // h-chunk into registers: octs 4s..4s+3 (32 h-values/lane, 16 VGPRs)
    uint4 xh[4];
#pragma unroll
    for (int k = 0; k < 4; ++k)
        xh[k] = hS[(size_t)bch * 4096 + (size_t)(s * 4 + k) * 64 + lane];

    __syncthreads();                    // aW ready

    unsigned acc[16];
#pragma unroll
    for (int r = 0; r < 16; ++r) acc[r] = hpk(-1.0f, -1.0f);

#pragma unroll
    for (int r = 0; r < 16; ++r) {
        const unsigned* a = &aW[r * 256 + s * 16];      // uniform
#pragma unroll
        for (int k = 0; k < 4; ++k) {
            acc[r] = pk_max(acc[r], pk_add(xh[k].x, a[k * 4 + 0]));
            acc[r] = pk_max(acc[r], pk_add(xh[k].y, a[k * 4 + 1]));
            acc[r] = pk_max(acc[r], pk_add(xh[k].z, a[k * 4 + 2]));
            acc[r] = pk_max(acc[r], pk_add(xh[k].w, a[k * 4 + 3]));
        }
    }

    {   // publish per-wave partials
#pragma unroll
        for (int r = 0; r < 16; ++r) {
            const unsigned f = pk_max(acc[r], acc[r] >> 16);
            red[(s * 16 + r) * 64 + lane] = (unsigned short)(f & 0xffffu);
        }
    }
    __syncthreads();

    {   // merge 16 chunk-partials per (row u, batch ln) -> f32
        const int u = tid >> 6, ln = tid & 63;
        unsigned m = red[u * 64 + ln];
#pragma unroll
        for (int ss = 1; ss < 16; ++ss)
            m = pk_max(m, (unsigned)red[(ss * 16 + u) * 64 + ln]);
        redf[u * 65 + ln] = h2f((unsigned short)(m & 0xffffu));
    }
    __syncthreads();

    {   // coalesced store: 4 batches x 16 consecutive o per wave (64-B segs)
        const int b = tid >> 4, ol = tid & 15;
        out[(size_t)(b0 + b) * 1024 + 16 * j2 + ol] = redf[ol * 65 + b];
    }
}

extern "C" void kernel_launch(void* const* d_in, const int* in_sizes, int n_in,
                              void* d_out, int out_size, void* d_ws, size_t ws_size,
                              hipStream_t stream) {
    const float* x    = (const float*)d_in[0];  // [256,1024] f32
    const int*   sel0 = (const int*)d_in[1];    // [512,1024] i32
    const int*   sel1 = (const int*)d_in[2];    // [1024,512] i32
    float* out = (float*)d_out;                 // [256,1024] f32

    uint4* hS = (uint4*)d_ws;                   // 256 KB f16 h slabs

    daa_l0<<<256, 1024, 0, stream>>>(x, sel0, hS);
    daa_l1<<<256, 1024, 0, stream>>>(hS, sel1, out);
}